// Round 13
// baseline (319.622 us; speedup 1.0000x reference)
//
#include <hip/hip_runtime.h>
#include <cstdint>

// ===== INSTRUMENTATION ROUND (round 13) =====
// Kernels functionally identical to round 11 (passed, 21.1us) EXCEPT:
//  - bq_query_kernel body wrapped in a x32 repeat loop (memory-clobber per
//    iter to defeat load hoisting) -> its dispatch becomes ~300us and WILL
//    appear in the rocprof top-5 with real VALUBusy/Occupancy/FETCH counters.
//  - launcher: build x8 + query x1  ->  dur = 8(B+n) + 32*Q_i + n + G.
// Combined with r11 (B+Q+2n+G=21.1) and r12 (Q+n=10.3) this fully decomposes
// the time AND diagnoses the query's bottleneck class. Restore next round.
//
// Membership decision replicates the numpy-f32 reference EXACTLY (round 5):
//   norms:   pure rn  n = rn(rn(xx + yy) + zz)         (ufunc passes)
//   dot:     FMA chain d = fma(z1,z2, fma(y1,y2, rn(x1*x2)))  (sgemm K-loop)
//   combine: pure rn  d2 = rn(rn(n1+n2) - rn(2*dot))
// Compute kernels carry #pragma clang fp contract(off); dot uses __fmaf_rn.
// DO NOT ALTER THIS CHAIN.

#define BQ_K    32
#define BQ_N1   8192
#define BQ_N2   16384
#define GDIM    12
#define NCELLS  (GDIM * GDIM * GDIM)  // 1728
#define NPART   4
#define PPTS    (BQ_N2 / NPART)       // 4096 per partition
#define HITCAP  128
#define GIDXCAP 512
#define QREP    32                    // measurement repeat factor

#define WS_META_OFF   0                      // uint[NCELLS*NPART] (27648)
#define WS_SORTED_OFF (NCELLS * NPART * 4)
#define WS_NEED       (WS_SORTED_OFF + BQ_N2 * 16)

__device__ __forceinline__ int bq_cell(float x, float y, float z) {
  int cx = min(max((int)(x * (float)GDIM), 0), GDIM - 1);
  int cy = min(max((int)(y * (float)GDIM), 0), GDIM - 1);
  int cz = min(max((int)(z * (float)GDIM), 0), GDIM - 1);
  return (cz * GDIM + cy) * GDIM + cx;
}

__global__ __launch_bounds__(1024) void bq_build_kernel(
    const float* __restrict__ p2, unsigned int* __restrict__ meta,
    float4* __restrict__ sorted) {
  __shared__ int s_cnt[NCELLS];
  __shared__ int s_wave[16];
  const int t = threadIdx.x;
  const int lane = t & 63, wv = t >> 6;
  const int p = blockIdx.x;
  const int pbase = p * PPTS;

  for (int i = t; i < NCELLS; i += 1024) s_cnt[i] = 0;
  __syncthreads();

  float px[4], py[4], pz[4];
  int pc[4];
#pragma unroll
  for (int k = 0; k < 4; ++k) {
    const int i = pbase + k * 1024 + t;
    px[k] = p2[i * 3 + 0];
    py[k] = p2[i * 3 + 1];
    pz[k] = p2[i * 3 + 2];
    pc[k] = bq_cell(px[k], py[k], pz[k]);
    atomicAdd(&s_cnt[pc[k]], 1);
  }
  __syncthreads();

  const int cell0 = t * 2;
  int c0 = 0, c1 = 0;
  if (cell0 < NCELLS) {
    c0 = s_cnt[cell0];
    c1 = s_cnt[cell0 + 1];
  }
  const int sum = c0 + c1;
  int inc = sum;
#pragma unroll
  for (int d = 1; d < 64; d <<= 1) {
    int v = __shfl_up(inc, d);
    if (lane >= d) inc += v;
  }
  if (lane == 63) s_wave[wv] = inc;
  __syncthreads();
  if (t == 0) {
    int r = 0;
    for (int w = 0; w < 16; ++w) { int v = s_wave[w]; s_wave[w] = r; r += v; }
  }
  __syncthreads();
  const int excl = s_wave[wv] + (inc - sum);
  if (cell0 < NCELLS) {
    const int st0 = pbase + excl;
    const int st1 = pbase + excl + c0;
    meta[cell0 * NPART + p] = ((unsigned)c0 << 16) | (unsigned)st0;
    meta[(cell0 + 1) * NPART + p] = ((unsigned)c1 << 16) | (unsigned)st1;
    s_cnt[cell0] = st0;
    s_cnt[cell0 + 1] = st1;
  }
  __syncthreads();

#pragma unroll
  for (int k = 0; k < 4; ++k) {
    const int i = pbase + k * 1024 + t;
    const int slot = atomicAdd(&s_cnt[pc[k]], 1);
    sorted[slot] = make_float4(px[k], py[k], pz[k], __int_as_float(i));
  }
}

__global__ __launch_bounds__(256) void bq_query_kernel(
    const float* __restrict__ p1, const float* __restrict__ p2,
    const unsigned int* __restrict__ meta, const float4* __restrict__ sorted,
    float* __restrict__ out) {
#pragma clang fp contract(off)
  const int lane = threadIdx.x & 63;
  const int wid = threadIdx.x >> 6;
  const int q = blockIdx.x * 4 + wid;

  __shared__ int s_gidx[4][GIDXCAP];
  __shared__ float4 s_hits[4][HITCAP];

  float* __restrict__ mapO = out + (size_t)q * BQ_K;
  float* __restrict__ numO = out + (size_t)BQ_N1 * BQ_K + q;
  float* __restrict__ ptsO =
      out + (size_t)BQ_N1 * BQ_K + BQ_N1 + (size_t)q * BQ_K * 3;

  // MEASUREMENT: repeat the full query body x32. Memory clobber forces
  // loop-invariant loads (p1, meta, sorted) to re-execute each iteration so
  // per-iteration cost ~= the real single-shot query cost. Output is
  // rewritten identically each iteration (deterministic, absmax 0).
  for (int rep = 0; rep < QREP; ++rep) {
    asm volatile("" ::: "memory");

    const float x1 = p1[q * 3 + 0];
    const float y1 = p1[q * 3 + 1];
    const float z1 = p1[q * 3 + 2];
    const float n1 = (x1 * x1 + y1 * y1) + z1 * z1;  // pure rn (contract off)
    const float rsq = (float)(0.08 * 0.08);
    const float prune_thr = 0.006413f;

    const int cx = min(max((int)(x1 * (float)GDIM), 0), GDIM - 1);
    const int cy = min(max((int)(y1 * (float)GDIM), 0), GDIM - 1);
    const int cz = min(max((int)(z1 * (float)GDIM), 0), GDIM - 1);

    int c0 = 0, c1 = 0;
    int st0 = 0, st1 = 0;
    if (lane < 54) {
      const int ci = lane >> 1;
      const int nx = cx + (ci % 3) - 1;
      const int ny = cy + ((ci / 3) % 3) - 1;
      const int nz = cz + (ci / 9) - 1;
      if (nx >= 0 && nx < GDIM && ny >= 0 && ny < GDIM && nz >= 0 &&
          nz < GDIM) {
        const float lx = (float)nx / 12.0f, hx = (float)(nx + 1) / 12.0f;
        const float ly = (float)ny / 12.0f, hy = (float)(ny + 1) / 12.0f;
        const float lz = (float)nz / 12.0f, hz = (float)(nz + 1) / 12.0f;
        const float dx = fmaxf(0.0f, fmaxf(lx - x1, x1 - hx));
        const float dy = fmaxf(0.0f, fmaxf(ly - y1, y1 - hy));
        const float dz = fmaxf(0.0f, fmaxf(lz - z1, z1 - hz));
        const float mind2 = dx * dx + dy * dy + dz * dz;
        if (mind2 <= prune_thr) {
          const int cc = (nz * GDIM + ny) * GDIM + nx;
          const uint2 m2 = *reinterpret_cast<const uint2*>(
              &meta[cc * NPART + (lane & 1) * 2]);
          c0 = (int)(m2.x >> 16); st0 = (int)(m2.x & 0xFFFFu);
          c1 = (int)(m2.y >> 16); st1 = (int)(m2.y & 0xFFFFu);
        }
      }
    }
    const int lsum = c0 + c1;
    int inc = lsum;
#pragma unroll
    for (int d = 1; d < 64; d <<= 1) {
      int v = __shfl_up(inc, d);
      if (lane >= d) inc += v;
    }
    const int T = __shfl(inc, 63);
    const int pref0 = inc - lsum;
    const int pref1 = pref0 + c0;

    const bool fast = (T <= GIDXCAP);
    int H = 0;
    if (fast) {
      for (int k = 0; k < c0; ++k) s_gidx[wid][pref0 + k] = st0 + k;
      for (int k = 0; k < c1; ++k) s_gidx[wid][pref1 + k] = st1 + k;

      for (int s0 = 0; s0 < T; s0 += 64) {
        const int s = s0 + lane;
        bool within = false;
        float x2 = 0.f, y2 = 0.f, z2 = 0.f;
        int idx = 0;
        if (s < T) {
          const int g = s_gidx[wid][s];
          const float4 pt = sorted[g];
          x2 = pt.x; y2 = pt.y; z2 = pt.z;
          idx = __float_as_int(pt.w);
          // EXACT reference FP chain (round 5) — do not alter.
          const float n2 = (x2 * x2 + y2 * y2) + z2 * z2;
          float dot = x2 * x1;
          dot = __fmaf_rn(y1, y2, dot);
          dot = __fmaf_rn(z1, z2, dot);
          const float nsum = n1 + n2;
          const float twodot = 2.0f * dot;
          const float d2 = nsum - twodot;
          within = (d2 <= rsq);
        }
        const unsigned long long b = __ballot(within);
        if (b) {
          if (within) {
            const int pos = H + (int)__popcll(b & ((1ull << lane) - 1ull));
            if (pos < HITCAP)
              s_hits[wid][pos] = make_float4(x2, y2, z2, __int_as_float(idx));
          }
          H += (int)__popcll(b);
        }
      }
    }

    if (fast && H <= HITCAP) {
      const int nh = min(H, BQ_K);
      float4 h0 = make_float4(0.f, 0.f, 0.f, __int_as_float(0x7fffffff));
      float4 h1 = h0;
      if (lane < H) h0 = s_hits[wid][lane];
      if (lane + 64 < H) h1 = s_hits[wid][lane + 64];
      const int i0 = __float_as_int(h0.w);
      const int i1 = __float_as_int(h1.w);
      int r0 = 0, r1 = 0;
      for (int j = 0; j < H; ++j) {
        const int bj = __float_as_int(s_hits[wid][j].w);
        r0 += (bj < i0) ? 1 : 0;
        r1 += (bj < i1) ? 1 : 0;
      }
      if (lane < H && r0 < BQ_K) {
        mapO[r0] = (float)i0;
        ptsO[r0 * 3 + 0] = h0.x;
        ptsO[r0 * 3 + 1] = h0.y;
        ptsO[r0 * 3 + 2] = h0.z;
      }
      if (lane + 64 < H && r1 < BQ_K) {
        mapO[r1] = (float)i1;
        ptsO[r1 * 3 + 0] = h1.x;
        ptsO[r1 * 3 + 1] = h1.y;
        ptsO[r1 * 3 + 2] = h1.z;
      }
      for (int sF = nh + lane; sF < BQ_K; sF += 64) {
        mapO[sF] = 0.0f;
        ptsO[sF * 3 + 0] = 0.0f;
        ptsO[sF * 3 + 1] = 0.0f;
        ptsO[sF * 3 + 2] = 0.0f;
      }
      if (lane == 0) numO[0] = (float)nh;
    } else {
      int filled = 0;
      for (int base = 0; base < BQ_N2; base += 64) {
        const int j = base + lane;
        const float x2 = p2[j * 3 + 0];
        const float y2 = p2[j * 3 + 1];
        const float z2 = p2[j * 3 + 2];
        const float n2 = (x2 * x2 + y2 * y2) + z2 * z2;
        float dot = x2 * x1;
        dot = __fmaf_rn(y1, y2, dot);
        dot = __fmaf_rn(z1, z2, dot);
        const float d2 = (n1 + n2) - 2.0f * dot;
        const bool within = (d2 <= rsq);
        const unsigned long long b = __ballot(within);
        if (b) {
          const int rank = (int)__popcll(b & ((1ull << lane) - 1ull));
          const int slot = filled + rank;
          if (within && slot < BQ_K) {
            mapO[slot] = (float)j;
            ptsO[slot * 3 + 0] = x2;
            ptsO[slot * 3 + 1] = y2;
            ptsO[slot * 3 + 2] = z2;
          }
          filled += (int)__popcll(b);
          if (filled >= BQ_K) { filled = BQ_K; break; }
        }
      }
      for (int sF = filled + lane; sF < BQ_K; sF += 64) {
        mapO[sF] = 0.0f;
        ptsO[sF * 3 + 0] = 0.0f;
        ptsO[sF * 3 + 1] = 0.0f;
        ptsO[sF * 3 + 2] = 0.0f;
      }
      if (lane == 0) numO[0] = (float)filled;
    }
  }
}

__global__ __launch_bounds__(256) void bq_seq_kernel(
    const float* __restrict__ p1, const float* __restrict__ p2,
    float* __restrict__ out) {
#pragma clang fp contract(off)
  const int lane = threadIdx.x & 63;
  const int wave = threadIdx.x >> 6;
  const int q = blockIdx.x * 4 + wave;
  const float x1 = p1[q * 3 + 0], y1 = p1[q * 3 + 1], z1 = p1[q * 3 + 2];
  const float n1 = (x1 * x1 + y1 * y1) + z1 * z1;
  const float rsq = (float)(0.08 * 0.08);
  float* mapO = out + (size_t)q * BQ_K;
  float* numO = out + (size_t)BQ_N1 * BQ_K + q;
  float* ptsO = out + (size_t)BQ_N1 * BQ_K + BQ_N1 + (size_t)q * BQ_K * 3;
  int filled = 0;
  for (int base = 0; base < BQ_N2; base += 64) {
    const int j = base + lane;
    const float x2 = p2[j * 3 + 0], y2 = p2[j * 3 + 1], z2 = p2[j * 3 + 2];
    const float n2 = (x2 * x2 + y2 * y2) + z2 * z2;
    float dot = x2 * x1;
    dot = __fmaf_rn(y1, y2, dot);
    dot = __fmaf_rn(z1, z2, dot);
    const float d2 = (n1 + n2) - 2.0f * dot;
    const bool within = (d2 <= rsq);
    const unsigned long long b = __ballot(within);
    if (b) {
      const int rank = (int)__popcll(b & ((1ull << lane) - 1ull));
      const int slot = filled + rank;
      if (within && slot < BQ_K) {
        mapO[slot] = (float)j;
        ptsO[slot * 3 + 0] = x2;
        ptsO[slot * 3 + 1] = y2;
        ptsO[slot * 3 + 2] = z2;
      }
      filled += (int)__popcll(b);
      if (filled >= BQ_K) { filled = BQ_K; break; }
    }
  }
  for (int s = filled + lane; s < BQ_K; s += 64) {
    mapO[s] = 0.0f;
    ptsO[s * 3 + 0] = 0.0f;
    ptsO[s * 3 + 1] = 0.0f;
    ptsO[s * 3 + 2] = 0.0f;
  }
  if (lane == 0) numO[0] = (float)filled;
}

extern "C" void kernel_launch(void* const* d_in, const int* in_sizes, int n_in,
                              void* d_out, int out_size, void* d_ws,
                              size_t ws_size, hipStream_t stream) {
  const float* p1 = (const float*)d_in[0];
  const float* p2 = (const float*)d_in[1];
  float* out = (float*)d_out;

  if (ws_size < (size_t)WS_NEED) {
    bq_seq_kernel<<<BQ_N1 / 4, 256, 0, stream>>>(p1, p2, out);
    return;
  }

  char* ws = (char*)d_ws;
  unsigned int* meta = (unsigned int*)(ws + WS_META_OFF);
  float4* sorted = (float4*)(ws + WS_SORTED_OFF);

  // MEASUREMENT: build x8 (idempotent; final meta/sorted state equivalent)
  // to expose 8(B+n); query x1 with internal x32 loop to expose counters.
  for (int rep = 0; rep < 8; ++rep) {
    bq_build_kernel<<<NPART, 1024, 0, stream>>>(p2, meta, sorted);
  }
  bq_query_kernel<<<BQ_N1 / 4, 256, 0, stream>>>(p1, p2, meta, sorted, out);
}

// Round 14
// 20.519 us; speedup vs baseline: 15.5768x; 15.5768x over previous
//
#include <hip/hip_runtime.h>
#include <cstdint>

// Ball query via 4-way-partitioned spatial grid, 2 dispatches.
// Round 14: query restructured to 2 QUERIES PER WAVE (32-lane groups) —
// r13 instrumentation proved query is VALU-issue-bound (VALUBusy 84%), so
// serving 2 queries with one wave instruction stream halves issue/query.
// Time decomposition (r11/r12/r13): G~9.4 fixed, n~1.0/node, B~0.4, Q~9.3.
//
// Membership decision replicates the numpy-f32 reference EXACTLY (round 5):
//   norms:   pure rn  n = rn(rn(xx + yy) + zz)         (ufunc passes)
//   dot:     FMA chain d = fma(z1,z2, fma(y1,y2, rn(x1*x2)))  (sgemm K-loop)
//   combine: pure rn  d2 = rn(rn(n1+n2) - rn(2*dot))
// Compute kernels carry #pragma clang fp contract(off); dot uses __fmaf_rn.
// DO NOT ALTER THIS CHAIN.
//
// Grid: 12^3 cells, cell 1/12 = 0.0833 > max accepted distance ~0.08000 =>
// accepted neighbors lie in the 27-cell neighborhood. AABB prune margin
// 1.2e-5 >> FP slop (verified absmax 0 since r8). Hits ranked by original
// index -> output deterministic despite atomic scatter order.
//
// Outputs (flat float32, concatenated):
//   [0        : N1*K)      mapping (index as float; unfilled -> 0)
//   [N1*K     : N1*K+N1)   num_neighbors (min(count, K))
//   [N1*K+N1  : +N1*K*3)   gathered coords (unfilled -> 0)

#define BQ_K    32
#define BQ_N1   8192
#define BQ_N2   16384
#define GDIM    12
#define NCELLS  (GDIM * GDIM * GDIM)  // 1728
#define NPART   4
#define PPTS    (BQ_N2 / NPART)       // 4096 per partition
#define QPB     8                     // queries (32-lane groups) per block
#define HITCAP  128                   // hits cap (data max ~60, +11 sigma)
#define GIDXCAP 384                   // candidate cap (avg ~182, +15 sigma)

#define WS_META_OFF   0                      // uint[NCELLS*NPART] (27648)
#define WS_SORTED_OFF (NCELLS * NPART * 4)   // float4[BQ_N2] (16B-aligned)
#define WS_NEED       (WS_SORTED_OFF + BQ_N2 * 16)

__device__ __forceinline__ int bq_cell(float x, float y, float z) {
  int cx = min(max((int)(x * (float)GDIM), 0), GDIM - 1);
  int cy = min(max((int)(y * (float)GDIM), 0), GDIM - 1);
  int cz = min(max((int)(z * (float)GDIM), 0), GDIM - 1);
  return (cz * GDIM + cy) * GDIM + cx;
}

// Grid build: unchanged (B ~ 0.4us, not worth touching).
__global__ __launch_bounds__(1024) void bq_build_kernel(
    const float* __restrict__ p2, unsigned int* __restrict__ meta,
    float4* __restrict__ sorted) {
  __shared__ int s_cnt[NCELLS];
  __shared__ int s_wave[16];
  const int t = threadIdx.x;
  const int lane = t & 63, wv = t >> 6;
  const int p = blockIdx.x;
  const int pbase = p * PPTS;

  for (int i = t; i < NCELLS; i += 1024) s_cnt[i] = 0;
  __syncthreads();

  float px[4], py[4], pz[4];
  int pc[4];
#pragma unroll
  for (int k = 0; k < 4; ++k) {
    const int i = pbase + k * 1024 + t;
    px[k] = p2[i * 3 + 0];
    py[k] = p2[i * 3 + 1];
    pz[k] = p2[i * 3 + 2];
    pc[k] = bq_cell(px[k], py[k], pz[k]);
    atomicAdd(&s_cnt[pc[k]], 1);
  }
  __syncthreads();

  const int cell0 = t * 2;
  int c0 = 0, c1 = 0;
  if (cell0 < NCELLS) {
    c0 = s_cnt[cell0];
    c1 = s_cnt[cell0 + 1];
  }
  const int sum = c0 + c1;
  int inc = sum;
#pragma unroll
  for (int d = 1; d < 64; d <<= 1) {
    int v = __shfl_up(inc, d);
    if (lane >= d) inc += v;
  }
  if (lane == 63) s_wave[wv] = inc;
  __syncthreads();
  if (t == 0) {
    int r = 0;
    for (int w = 0; w < 16; ++w) { int v = s_wave[w]; s_wave[w] = r; r += v; }
  }
  __syncthreads();
  const int excl = s_wave[wv] + (inc - sum);
  if (cell0 < NCELLS) {
    const int st0 = pbase + excl;
    const int st1 = pbase + excl + c0;
    meta[cell0 * NPART + p] = ((unsigned)c0 << 16) | (unsigned)st0;
    meta[(cell0 + 1) * NPART + p] = ((unsigned)c1 << 16) | (unsigned)st1;
    s_cnt[cell0] = st0;
    s_cnt[cell0 + 1] = st1;
  }
  __syncthreads();

#pragma unroll
  for (int k = 0; k < 4; ++k) {
    const int i = pbase + k * 1024 + t;
    const int slot = atomicAdd(&s_cnt[pc[k]], 1);
    sorted[slot] = make_float4(px[k], py[k], pz[k], __int_as_float(i));
  }
}

// Query: one 32-lane group per query; 2 groups share each wave's
// instruction stream; 8 groups per 256-thread block. No barriers needed
// (each group's LDS slab is touched only by lanes of its own wave).
__global__ __launch_bounds__(256) void bq_query_kernel(
    const float* __restrict__ p1, const float* __restrict__ p2,
    const unsigned int* __restrict__ meta, const float4* __restrict__ sorted,
    float* __restrict__ out) {
#pragma clang fp contract(off)
  const int t = threadIdx.x;
  const int lane = t & 63;   // lane within wave
  const int gl = t & 31;     // lane within group
  const int gid = t >> 5;    // group within block (0..7)
  const int half = lane >> 5;
  const int q = blockIdx.x * QPB + gid;

  __shared__ int s_gidx[QPB][GIDXCAP];
  __shared__ int s_hits[QPB][HITCAP];

  const float x1 = p1[q * 3 + 0];
  const float y1 = p1[q * 3 + 1];
  const float z1 = p1[q * 3 + 2];
  const float n1 = (x1 * x1 + y1 * y1) + z1 * z1;  // pure rn (contract off)
  const float rsq = (float)(0.08 * 0.08);
  const float prune_thr = 0.006413f;  // rsq*1.002 (safe AABB bound)

  const int cx = min(max((int)(x1 * (float)GDIM), 0), GDIM - 1);
  const int cy = min(max((int)(y1 * (float)GDIM), 0), GDIM - 1);
  const int cz = min(max((int)(z1 * (float)GDIM), 0), GDIM - 1);

  // Lane gl < 27 owns neighbor cell gl: ONE uint4 load covers its 4 runs.
  int c0 = 0, c1 = 0, c2 = 0, c3 = 0;
  int st0 = 0, st1 = 0, st2 = 0, st3 = 0;
  if (gl < 27) {
    const int nx = cx + (gl % 3) - 1;
    const int ny = cy + ((gl / 3) % 3) - 1;
    const int nz = cz + (gl / 9) - 1;
    if (nx >= 0 && nx < GDIM && ny >= 0 && ny < GDIM && nz >= 0 && nz < GDIM) {
      const float lx = (float)nx / 12.0f, hx = (float)(nx + 1) / 12.0f;
      const float ly = (float)ny / 12.0f, hy = (float)(ny + 1) / 12.0f;
      const float lz = (float)nz / 12.0f, hz = (float)(nz + 1) / 12.0f;
      const float dx = fmaxf(0.0f, fmaxf(lx - x1, x1 - hx));
      const float dy = fmaxf(0.0f, fmaxf(ly - y1, y1 - hy));
      const float dz = fmaxf(0.0f, fmaxf(lz - z1, z1 - hz));
      const float mind2 = dx * dx + dy * dy + dz * dz;
      if (mind2 <= prune_thr) {
        const int cc = (nz * GDIM + ny) * GDIM + nx;
        const uint4 m4 = *reinterpret_cast<const uint4*>(&meta[cc * NPART]);
        c0 = (int)(m4.x >> 16); st0 = (int)(m4.x & 0xFFFFu);
        c1 = (int)(m4.y >> 16); st1 = (int)(m4.y & 0xFFFFu);
        c2 = (int)(m4.z >> 16); st2 = (int)(m4.z & 0xFFFFu);
        c3 = (int)(m4.w >> 16); st3 = (int)(m4.w & 0xFFFFu);
      }
    }
  }
  // Width-32 inclusive scan of per-lane sums.
  const int lsum = c0 + c1 + c2 + c3;
  int inc = lsum;
#pragma unroll
  for (int d = 1; d < 32; d <<= 1) {
    int v = __shfl_up(inc, d, 32);
    if (gl >= d) inc += v;
  }
  const int T = __shfl(inc, 31, 32);
  const int pref0 = inc - lsum;
  const int pref1 = pref0 + c0;
  const int pref2 = pref1 + c1;
  const int pref3 = pref2 + c2;

  float* __restrict__ mapO = out + (size_t)q * BQ_K;
  float* __restrict__ numO = out + (size_t)BQ_N1 * BQ_K + q;
  float* __restrict__ ptsO =
      out + (size_t)BQ_N1 * BQ_K + BQ_N1 + (size_t)q * BQ_K * 3;

  const bool fast = (T <= GIDXCAP);
  int H = 0;
  if (fast) {
    // Materialize candidate table (each lane writes its 4 short runs).
    for (int k = 0; k < c0; ++k) s_gidx[gid][pref0 + k] = st0 + k;
    for (int k = 0; k < c1; ++k) s_gidx[gid][pref1 + k] = st1 + k;
    for (int k = 0; k < c2; ++k) s_gidx[gid][pref2 + k] = st2 + k;
    for (int k = 0; k < c3; ++k) s_gidx[gid][pref3 + k] = st3 + k;

    // Sweep: 32 candidates/iter; hits recorded as idx only.
    for (int s0 = 0; s0 < T; s0 += 32) {
      const int s = s0 + gl;
      bool within = false;
      int idx = 0;
      if (s < T) {
        const int g = s_gidx[gid][s];
        const float4 pt = sorted[g];
        const float x2 = pt.x, y2 = pt.y, z2 = pt.z;
        idx = __float_as_int(pt.w);
        // EXACT reference FP chain (round 5) — do not alter.
        const float n2 = (x2 * x2 + y2 * y2) + z2 * z2;
        float dot = x2 * x1;
        dot = __fmaf_rn(y1, y2, dot);
        dot = __fmaf_rn(z1, z2, dot);
        const float nsum = n1 + n2;
        const float twodot = 2.0f * dot;
        const float d2 = nsum - twodot;
        within = (d2 <= rsq);
      }
      const unsigned int b32 =
          (unsigned int)(__ballot(within) >> (half << 5));
      if (b32) {
        if (within) {
          const int pos = H + (int)__popc(b32 & ((1u << gl) - 1u));
          if (pos < HITCAP) s_hits[gid][pos] = idx;
        }
        H += (int)__popc(b32);
      }
    }
  }

  if (fast && H <= HITCAP) {
    const int nh = min(H, BQ_K);
    const int i0 = (gl < H) ? s_hits[gid][gl] : 0x7fffffff;
    const int i1 = (gl + 32 < H) ? s_hits[gid][gl + 32] : 0x7fffffff;
    int r0 = 0, r1 = 0;
    if (H <= 64) {
      for (int j = 0; j < H; ++j) {  // group-uniform broadcast reads
        const int bj = s_hits[gid][j];
        r0 += (bj < i0) ? 1 : 0;
        r1 += (bj < i1) ? 1 : 0;
      }
    } else {
      const int i2 = (gl + 64 < H) ? s_hits[gid][gl + 64] : 0x7fffffff;
      const int i3 = (gl + 96 < H) ? s_hits[gid][gl + 96] : 0x7fffffff;
      int r2 = 0, r3 = 0;
      for (int j = 0; j < H; ++j) {
        const int bj = s_hits[gid][j];
        r0 += (bj < i0) ? 1 : 0;
        r1 += (bj < i1) ? 1 : 0;
        r2 += (bj < i2) ? 1 : 0;
        r3 += (bj < i3) ? 1 : 0;
      }
      if (gl + 64 < H && r2 < BQ_K) {
        mapO[r2] = (float)i2;
        ptsO[r2 * 3 + 0] = p2[i2 * 3 + 0];
        ptsO[r2 * 3 + 1] = p2[i2 * 3 + 1];
        ptsO[r2 * 3 + 2] = p2[i2 * 3 + 2];
      }
      if (gl + 96 < H && r3 < BQ_K) {
        mapO[r3] = (float)i3;
        ptsO[r3 * 3 + 0] = p2[i3 * 3 + 0];
        ptsO[r3 * 3 + 1] = p2[i3 * 3 + 1];
        ptsO[r3 * 3 + 2] = p2[i3 * 3 + 2];
      }
    }
    if (gl < H && r0 < BQ_K) {
      mapO[r0] = (float)i0;
      ptsO[r0 * 3 + 0] = p2[i0 * 3 + 0];
      ptsO[r0 * 3 + 1] = p2[i0 * 3 + 1];
      ptsO[r0 * 3 + 2] = p2[i0 * 3 + 2];
    }
    if (gl + 32 < H && r1 < BQ_K) {
      mapO[r1] = (float)i1;
      ptsO[r1 * 3 + 0] = p2[i1 * 3 + 0];
      ptsO[r1 * 3 + 1] = p2[i1 * 3 + 1];
      ptsO[r1 * 3 + 2] = p2[i1 * 3 + 2];
    }
    // Zero-fill: lane gl owns output slot gl (BQ_K == 32 slots).
    if (gl >= nh) {
      mapO[gl] = 0.0f;
      ptsO[gl * 3 + 0] = 0.0f;
      ptsO[gl * 3 + 1] = 0.0f;
      ptsO[gl * 3 + 2] = 0.0f;
    }
    if (gl == 0) numO[0] = (float)nh;
  } else {
    // Exact 32-lane sequential fallback (capacity overflow; P ~ 0).
    int filled = 0;
    for (int base = 0; base < BQ_N2; base += 32) {
      const int j = base + gl;
      const float x2 = p2[j * 3 + 0];
      const float y2 = p2[j * 3 + 1];
      const float z2 = p2[j * 3 + 2];
      const float n2 = (x2 * x2 + y2 * y2) + z2 * z2;
      float dot = x2 * x1;
      dot = __fmaf_rn(y1, y2, dot);
      dot = __fmaf_rn(z1, z2, dot);
      const float d2 = (n1 + n2) - 2.0f * dot;
      const bool within = (d2 <= rsq);
      const unsigned int b32 =
          (unsigned int)(__ballot(within) >> (half << 5));
      if (b32) {
        const int rank = (int)__popc(b32 & ((1u << gl) - 1u));
        const int slot = filled + rank;
        if (within && slot < BQ_K) {
          mapO[slot] = (float)j;
          ptsO[slot * 3 + 0] = x2;
          ptsO[slot * 3 + 1] = y2;
          ptsO[slot * 3 + 2] = z2;
        }
        filled += (int)__popc(b32);
        if (filled >= BQ_K) { filled = BQ_K; break; }
      }
    }
    if (gl >= filled) {
      mapO[gl] = 0.0f;
      ptsO[gl * 3 + 0] = 0.0f;
      ptsO[gl * 3 + 1] = 0.0f;
      ptsO[gl * 3 + 2] = 0.0f;
    }
    if (gl == 0) numO[0] = (float)filled;
  }
}

// Round-5 brute-force kernel, whole-problem fallback if ws too small.
__global__ __launch_bounds__(256) void bq_seq_kernel(
    const float* __restrict__ p1, const float* __restrict__ p2,
    float* __restrict__ out) {
#pragma clang fp contract(off)
  const int lane = threadIdx.x & 63;
  const int wave = threadIdx.x >> 6;
  const int q = blockIdx.x * 4 + wave;
  const float x1 = p1[q * 3 + 0], y1 = p1[q * 3 + 1], z1 = p1[q * 3 + 2];
  const float n1 = (x1 * x1 + y1 * y1) + z1 * z1;
  const float rsq = (float)(0.08 * 0.08);
  float* mapO = out + (size_t)q * BQ_K;
  float* numO = out + (size_t)BQ_N1 * BQ_K + q;
  float* ptsO = out + (size_t)BQ_N1 * BQ_K + BQ_N1 + (size_t)q * BQ_K * 3;
  int filled = 0;
  for (int base = 0; base < BQ_N2; base += 64) {
    const int j = base + lane;
    const float x2 = p2[j * 3 + 0], y2 = p2[j * 3 + 1], z2 = p2[j * 3 + 2];
    const float n2 = (x2 * x2 + y2 * y2) + z2 * z2;
    float dot = x2 * x1;
    dot = __fmaf_rn(y1, y2, dot);
    dot = __fmaf_rn(z1, z2, dot);
    const float d2 = (n1 + n2) - 2.0f * dot;
    const bool within = (d2 <= rsq);
    const unsigned long long b = __ballot(within);
    if (b) {
      const int rank = (int)__popcll(b & ((1ull << lane) - 1ull));
      const int slot = filled + rank;
      if (within && slot < BQ_K) {
        mapO[slot] = (float)j;
        ptsO[slot * 3 + 0] = x2;
        ptsO[slot * 3 + 1] = y2;
        ptsO[slot * 3 + 2] = z2;
      }
      filled += (int)__popcll(b);
      if (filled >= BQ_K) { filled = BQ_K; break; }
    }
  }
  for (int s = filled + lane; s < BQ_K; s += 64) {
    mapO[s] = 0.0f;
    ptsO[s * 3 + 0] = 0.0f;
    ptsO[s * 3 + 1] = 0.0f;
    ptsO[s * 3 + 2] = 0.0f;
  }
  if (lane == 0) numO[0] = (float)filled;
}

extern "C" void kernel_launch(void* const* d_in, const int* in_sizes, int n_in,
                              void* d_out, int out_size, void* d_ws,
                              size_t ws_size, hipStream_t stream) {
  const float* p1 = (const float*)d_in[0];
  const float* p2 = (const float*)d_in[1];
  float* out = (float*)d_out;

  if (ws_size < (size_t)WS_NEED) {
    bq_seq_kernel<<<BQ_N1 / 4, 256, 0, stream>>>(p1, p2, out);
    return;
  }

  char* ws = (char*)d_ws;
  unsigned int* meta = (unsigned int*)(ws + WS_META_OFF);
  float4* sorted = (float4*)(ws + WS_SORTED_OFF);

  bq_build_kernel<<<NPART, 1024, 0, stream>>>(p2, meta, sorted);
  bq_query_kernel<<<BQ_N1 / QPB, 256, 0, stream>>>(p1, p2, meta, sorted, out);
}

// Round 15
// 19.877 us; speedup vs baseline: 16.0797x; 1.0323x over previous
//
#include <hip/hip_runtime.h>
#include <cstdint>

// Ball query via 4-way-partitioned spatial grid, 2 dispatches.
// Round 15: rank-by-index epilogue replaced with a 64-element register
// bitonic sort (shfl_xor network) -> K smallest hit indices land ascending,
// one per lane, no LDS rank loop. (r13 decomposition: G~9.4 fixed, n~1.0,
// B~0.4, Q~8.7 VALU-issue-bound; rank loop was Q's largest overhead block.)
//
// Membership decision replicates the numpy-f32 reference EXACTLY (round 5):
//   norms:   pure rn  n = rn(rn(xx + yy) + zz)         (ufunc passes)
//   dot:     FMA chain d = fma(z1,z2, fma(y1,y2, rn(x1*x2)))  (sgemm K-loop)
//   combine: pure rn  d2 = rn(rn(n1+n2) - rn(2*dot))
// Compute kernels carry #pragma clang fp contract(off); dot uses __fmaf_rn.
// DO NOT ALTER THIS CHAIN.
//
// Grid: 12^3 cells, cell 1/12 = 0.0833 > max accepted distance ~0.08000 =>
// accepted neighbors lie in the 27-cell neighborhood. AABB prune margin
// 1.2e-5 >> FP slop (verified absmax 0 since r8). Hits ranked by original
// index -> output deterministic despite atomic scatter order.
//
// Outputs (flat float32, concatenated):
//   [0        : N1*K)      mapping (index as float; unfilled -> 0)
//   [N1*K     : N1*K+N1)   num_neighbors (min(count, K))
//   [N1*K+N1  : +N1*K*3)   gathered coords (unfilled -> 0)

#define BQ_K    32
#define BQ_N1   8192
#define BQ_N2   16384
#define GDIM    12
#define NCELLS  (GDIM * GDIM * GDIM)  // 1728
#define NPART   4
#define PPTS    (BQ_N2 / NPART)       // 4096 per partition
#define QPB     8                     // queries (32-lane groups) per block
#define HITCAP  128                   // hits cap (data max ~60)
#define GIDXCAP 384                   // candidate cap (avg ~182)

#define WS_META_OFF   0                      // uint[NCELLS*NPART] (27648)
#define WS_SORTED_OFF (NCELLS * NPART * 4)   // float4[BQ_N2] (16B-aligned)
#define WS_NEED       (WS_SORTED_OFF + BQ_N2 * 16)

__device__ __forceinline__ int bq_cell(float x, float y, float z) {
  int cx = min(max((int)(x * (float)GDIM), 0), GDIM - 1);
  int cy = min(max((int)(y * (float)GDIM), 0), GDIM - 1);
  int cz = min(max((int)(z * (float)GDIM), 0), GDIM - 1);
  return (cz * GDIM + cy) * GDIM + cx;
}

// Ascending 32-lane bitonic sort of one int per lane (within 32-lane group).
__device__ __forceinline__ int bq_bsort32(int v, int gl) {
#pragma unroll
  for (int k = 2; k <= 32; k <<= 1) {
#pragma unroll
    for (int j = k >> 1; j > 0; j >>= 1) {
      const int o = __shfl_xor(v, j, 32);
      const bool up = ((gl & k) == 0);
      const bool lower = ((gl & j) == 0);
      v = (up == lower) ? min(v, o) : max(v, o);
    }
  }
  return v;
}

// Grid build: unchanged (B ~ 0.4us).
__global__ __launch_bounds__(1024) void bq_build_kernel(
    const float* __restrict__ p2, unsigned int* __restrict__ meta,
    float4* __restrict__ sorted) {
  __shared__ int s_cnt[NCELLS];
  __shared__ int s_wave[16];
  const int t = threadIdx.x;
  const int lane = t & 63, wv = t >> 6;
  const int p = blockIdx.x;
  const int pbase = p * PPTS;

  for (int i = t; i < NCELLS; i += 1024) s_cnt[i] = 0;
  __syncthreads();

  float px[4], py[4], pz[4];
  int pc[4];
#pragma unroll
  for (int k = 0; k < 4; ++k) {
    const int i = pbase + k * 1024 + t;
    px[k] = p2[i * 3 + 0];
    py[k] = p2[i * 3 + 1];
    pz[k] = p2[i * 3 + 2];
    pc[k] = bq_cell(px[k], py[k], pz[k]);
    atomicAdd(&s_cnt[pc[k]], 1);
  }
  __syncthreads();

  const int cell0 = t * 2;
  int c0 = 0, c1 = 0;
  if (cell0 < NCELLS) {
    c0 = s_cnt[cell0];
    c1 = s_cnt[cell0 + 1];
  }
  const int sum = c0 + c1;
  int inc = sum;
#pragma unroll
  for (int d = 1; d < 64; d <<= 1) {
    int v = __shfl_up(inc, d);
    if (lane >= d) inc += v;
  }
  if (lane == 63) s_wave[wv] = inc;
  __syncthreads();
  if (t == 0) {
    int r = 0;
    for (int w = 0; w < 16; ++w) { int v = s_wave[w]; s_wave[w] = r; r += v; }
  }
  __syncthreads();
  const int excl = s_wave[wv] + (inc - sum);
  if (cell0 < NCELLS) {
    const int st0 = pbase + excl;
    const int st1 = pbase + excl + c0;
    meta[cell0 * NPART + p] = ((unsigned)c0 << 16) | (unsigned)st0;
    meta[(cell0 + 1) * NPART + p] = ((unsigned)c1 << 16) | (unsigned)st1;
    s_cnt[cell0] = st0;
    s_cnt[cell0 + 1] = st1;
  }
  __syncthreads();

#pragma unroll
  for (int k = 0; k < 4; ++k) {
    const int i = pbase + k * 1024 + t;
    const int slot = atomicAdd(&s_cnt[pc[k]], 1);
    sorted[slot] = make_float4(px[k], py[k], pz[k], __int_as_float(i));
  }
}

// Query: one 32-lane group per query; 2 groups per wave share the
// instruction stream; 8 groups per 256-thread block. No barriers needed.
__global__ __launch_bounds__(256) void bq_query_kernel(
    const float* __restrict__ p1, const float* __restrict__ p2,
    const unsigned int* __restrict__ meta, const float4* __restrict__ sorted,
    float* __restrict__ out) {
#pragma clang fp contract(off)
  const int t = threadIdx.x;
  const int lane = t & 63;
  const int gl = t & 31;
  const int gid = t >> 5;
  const int half = lane >> 5;
  const int q = blockIdx.x * QPB + gid;

  __shared__ int s_gidx[QPB][GIDXCAP];
  __shared__ int s_hits[QPB][HITCAP];

  const float x1 = p1[q * 3 + 0];
  const float y1 = p1[q * 3 + 1];
  const float z1 = p1[q * 3 + 2];
  const float n1 = (x1 * x1 + y1 * y1) + z1 * z1;  // pure rn (contract off)
  const float rsq = (float)(0.08 * 0.08);
  const float prune_thr = 0.006413f;  // rsq*1.002 (safe AABB bound)

  const int cx = min(max((int)(x1 * (float)GDIM), 0), GDIM - 1);
  const int cy = min(max((int)(y1 * (float)GDIM), 0), GDIM - 1);
  const int cz = min(max((int)(z1 * (float)GDIM), 0), GDIM - 1);

  // Lane gl < 27 owns neighbor cell gl: ONE uint4 load covers its 4 runs.
  int c0 = 0, c1 = 0, c2 = 0, c3 = 0;
  int st0 = 0, st1 = 0, st2 = 0, st3 = 0;
  if (gl < 27) {
    const int nx = cx + (gl % 3) - 1;
    const int ny = cy + ((gl / 3) % 3) - 1;
    const int nz = cz + (gl / 9) - 1;
    if (nx >= 0 && nx < GDIM && ny >= 0 && ny < GDIM && nz >= 0 && nz < GDIM) {
      const float lx = (float)nx / 12.0f, hx = (float)(nx + 1) / 12.0f;
      const float ly = (float)ny / 12.0f, hy = (float)(ny + 1) / 12.0f;
      const float lz = (float)nz / 12.0f, hz = (float)(nz + 1) / 12.0f;
      const float dx = fmaxf(0.0f, fmaxf(lx - x1, x1 - hx));
      const float dy = fmaxf(0.0f, fmaxf(ly - y1, y1 - hy));
      const float dz = fmaxf(0.0f, fmaxf(lz - z1, z1 - hz));
      const float mind2 = dx * dx + dy * dy + dz * dz;
      if (mind2 <= prune_thr) {
        const int cc = (nz * GDIM + ny) * GDIM + nx;
        const uint4 m4 = *reinterpret_cast<const uint4*>(&meta[cc * NPART]);
        c0 = (int)(m4.x >> 16); st0 = (int)(m4.x & 0xFFFFu);
        c1 = (int)(m4.y >> 16); st1 = (int)(m4.y & 0xFFFFu);
        c2 = (int)(m4.z >> 16); st2 = (int)(m4.z & 0xFFFFu);
        c3 = (int)(m4.w >> 16); st3 = (int)(m4.w & 0xFFFFu);
      }
    }
  }
  // Width-32 inclusive scan of per-lane sums.
  const int lsum = c0 + c1 + c2 + c3;
  int inc = lsum;
#pragma unroll
  for (int d = 1; d < 32; d <<= 1) {
    int v = __shfl_up(inc, d, 32);
    if (gl >= d) inc += v;
  }
  const int T = __shfl(inc, 31, 32);
  const int pref0 = inc - lsum;
  const int pref1 = pref0 + c0;
  const int pref2 = pref1 + c1;
  const int pref3 = pref2 + c2;

  float* __restrict__ mapO = out + (size_t)q * BQ_K;
  float* __restrict__ numO = out + (size_t)BQ_N1 * BQ_K + q;
  float* __restrict__ ptsO =
      out + (size_t)BQ_N1 * BQ_K + BQ_N1 + (size_t)q * BQ_K * 3;

  const bool fast = (T <= GIDXCAP);
  int H = 0;
  if (fast) {
    // Materialize candidate table (each lane writes its 4 short runs).
    for (int k = 0; k < c0; ++k) s_gidx[gid][pref0 + k] = st0 + k;
    for (int k = 0; k < c1; ++k) s_gidx[gid][pref1 + k] = st1 + k;
    for (int k = 0; k < c2; ++k) s_gidx[gid][pref2 + k] = st2 + k;
    for (int k = 0; k < c3; ++k) s_gidx[gid][pref3 + k] = st3 + k;

    // Sweep: 32 candidates/iter; hits recorded as idx only.
    for (int s0 = 0; s0 < T; s0 += 32) {
      const int s = s0 + gl;
      bool within = false;
      int idx = 0;
      if (s < T) {
        const int g = s_gidx[gid][s];
        const float4 pt = sorted[g];
        const float x2 = pt.x, y2 = pt.y, z2 = pt.z;
        idx = __float_as_int(pt.w);
        // EXACT reference FP chain (round 5) — do not alter.
        const float n2 = (x2 * x2 + y2 * y2) + z2 * z2;
        float dot = x2 * x1;
        dot = __fmaf_rn(y1, y2, dot);
        dot = __fmaf_rn(z1, z2, dot);
        const float nsum = n1 + n2;
        const float twodot = 2.0f * dot;
        const float d2 = nsum - twodot;
        within = (d2 <= rsq);
      }
      const unsigned int b32 =
          (unsigned int)(__ballot(within) >> (half << 5));
      if (b32) {
        if (within) {
          const int pos = H + (int)__popc(b32 & ((1u << gl) - 1u));
          if (pos < HITCAP) s_hits[gid][pos] = idx;
        }
        H += (int)__popc(b32);
      }
    }
  }

  if (fast && H <= 64) {
    // Bitonic epilogue: sort two 32-vectors, merge, keep 32 smallest sorted.
    const int nh = min(H, BQ_K);
    int v0 = (gl < H) ? s_hits[gid][gl] : 0x7fffffff;
    int v1 = (gl + 32 < H) ? s_hits[gid][gl + 32] : 0x7fffffff;
    v0 = bq_bsort32(v0, gl);
    v1 = bq_bsort32(v1, gl);
    const int v1r = __shfl(v1, 31 - gl, 32);  // descending copy
    int m = min(v0, v1r);                     // 32 smallest, bitonic order
#pragma unroll
    for (int j = 16; j > 0; j >>= 1) {        // clean to ascending
      const int o = __shfl_xor(m, j, 32);
      m = ((gl & j) == 0) ? min(m, o) : max(m, o);
    }
    if (gl < nh) {
      mapO[gl] = (float)m;
      ptsO[gl * 3 + 0] = p2[m * 3 + 0];
      ptsO[gl * 3 + 1] = p2[m * 3 + 1];
      ptsO[gl * 3 + 2] = p2[m * 3 + 2];
    } else {
      mapO[gl] = 0.0f;
      ptsO[gl * 3 + 0] = 0.0f;
      ptsO[gl * 3 + 1] = 0.0f;
      ptsO[gl * 3 + 2] = 0.0f;
    }
    if (gl == 0) numO[0] = (float)nh;
  } else if (fast && H <= HITCAP) {
    // Rare 64 < H <= 128: rank-loop path (4 comparators). P ~ 0.
    const int nh = min(H, BQ_K);
    const int i0 = (gl < H) ? s_hits[gid][gl] : 0x7fffffff;
    const int i1 = (gl + 32 < H) ? s_hits[gid][gl + 32] : 0x7fffffff;
    const int i2 = (gl + 64 < H) ? s_hits[gid][gl + 64] : 0x7fffffff;
    const int i3 = (gl + 96 < H) ? s_hits[gid][gl + 96] : 0x7fffffff;
    int r0 = 0, r1 = 0, r2 = 0, r3 = 0;
    for (int j = 0; j < H; ++j) {
      const int bj = s_hits[gid][j];
      r0 += (bj < i0) ? 1 : 0;
      r1 += (bj < i1) ? 1 : 0;
      r2 += (bj < i2) ? 1 : 0;
      r3 += (bj < i3) ? 1 : 0;
    }
    if (gl < H && r0 < BQ_K) {
      mapO[r0] = (float)i0;
      ptsO[r0 * 3 + 0] = p2[i0 * 3 + 0];
      ptsO[r0 * 3 + 1] = p2[i0 * 3 + 1];
      ptsO[r0 * 3 + 2] = p2[i0 * 3 + 2];
    }
    if (gl + 32 < H && r1 < BQ_K) {
      mapO[r1] = (float)i1;
      ptsO[r1 * 3 + 0] = p2[i1 * 3 + 0];
      ptsO[r1 * 3 + 1] = p2[i1 * 3 + 1];
      ptsO[r1 * 3 + 2] = p2[i1 * 3 + 2];
    }
    if (gl + 64 < H && r2 < BQ_K) {
      mapO[r2] = (float)i2;
      ptsO[r2 * 3 + 0] = p2[i2 * 3 + 0];
      ptsO[r2 * 3 + 1] = p2[i2 * 3 + 1];
      ptsO[r2 * 3 + 2] = p2[i2 * 3 + 2];
    }
    if (gl + 96 < H && r3 < BQ_K) {
      mapO[r3] = (float)i3;
      ptsO[r3 * 3 + 0] = p2[i3 * 3 + 0];
      ptsO[r3 * 3 + 1] = p2[i3 * 3 + 1];
      ptsO[r3 * 3 + 2] = p2[i3 * 3 + 2];
    }
    if (gl >= nh) {
      mapO[gl] = 0.0f;
      ptsO[gl * 3 + 0] = 0.0f;
      ptsO[gl * 3 + 1] = 0.0f;
      ptsO[gl * 3 + 2] = 0.0f;
    }
    if (gl == 0) numO[0] = (float)nh;
  } else {
    // Exact 32-lane sequential fallback (capacity overflow; P ~ 0).
    int filled = 0;
    for (int base = 0; base < BQ_N2; base += 32) {
      const int j = base + gl;
      const float x2 = p2[j * 3 + 0];
      const float y2 = p2[j * 3 + 1];
      const float z2 = p2[j * 3 + 2];
      const float n2 = (x2 * x2 + y2 * y2) + z2 * z2;
      float dot = x2 * x1;
      dot = __fmaf_rn(y1, y2, dot);
      dot = __fmaf_rn(z1, z2, dot);
      const float d2 = (n1 + n2) - 2.0f * dot;
      const bool within = (d2 <= rsq);
      const unsigned int b32 =
          (unsigned int)(__ballot(within) >> (half << 5));
      if (b32) {
        const int rank = (int)__popc(b32 & ((1u << gl) - 1u));
        const int slot = filled + rank;
        if (within && slot < BQ_K) {
          mapO[slot] = (float)j;
          ptsO[slot * 3 + 0] = x2;
          ptsO[slot * 3 + 1] = y2;
          ptsO[slot * 3 + 2] = z2;
        }
        filled += (int)__popc(b32);
        if (filled >= BQ_K) { filled = BQ_K; break; }
      }
    }
    if (gl >= filled) {
      mapO[gl] = 0.0f;
      ptsO[gl * 3 + 0] = 0.0f;
      ptsO[gl * 3 + 1] = 0.0f;
      ptsO[gl * 3 + 2] = 0.0f;
    }
    if (gl == 0) numO[0] = (float)filled;
  }
}

// Round-5 brute-force kernel, whole-problem fallback if ws too small.
__global__ __launch_bounds__(256) void bq_seq_kernel(
    const float* __restrict__ p1, const float* __restrict__ p2,
    float* __restrict__ out) {
#pragma clang fp contract(off)
  const int lane = threadIdx.x & 63;
  const int wave = threadIdx.x >> 6;
  const int q = blockIdx.x * 4 + wave;
  const float x1 = p1[q * 3 + 0], y1 = p1[q * 3 + 1], z1 = p1[q * 3 + 2];
  const float n1 = (x1 * x1 + y1 * y1) + z1 * z1;
  const float rsq = (float)(0.08 * 0.08);
  float* mapO = out + (size_t)q * BQ_K;
  float* numO = out + (size_t)BQ_N1 * BQ_K + q;
  float* ptsO = out + (size_t)BQ_N1 * BQ_K + BQ_N1 + (size_t)q * BQ_K * 3;
  int filled = 0;
  for (int base = 0; base < BQ_N2; base += 64) {
    const int j = base + lane;
    const float x2 = p2[j * 3 + 0], y2 = p2[j * 3 + 1], z2 = p2[j * 3 + 2];
    const float n2 = (x2 * x2 + y2 * y2) + z2 * z2;
    float dot = x2 * x1;
    dot = __fmaf_rn(y1, y2, dot);
    dot = __fmaf_rn(z1, z2, dot);
    const float d2 = (n1 + n2) - 2.0f * dot;
    const bool within = (d2 <= rsq);
    const unsigned long long b = __ballot(within);
    if (b) {
      const int rank = (int)__popcll(b & ((1ull << lane) - 1ull));
      const int slot = filled + rank;
      if (within && slot < BQ_K) {
        mapO[slot] = (float)j;
        ptsO[slot * 3 + 0] = x2;
        ptsO[slot * 3 + 1] = y2;
        ptsO[slot * 3 + 2] = z2;
      }
      filled += (int)__popcll(b);
      if (filled >= BQ_K) { filled = BQ_K; break; }
    }
  }
  for (int s = filled + lane; s < BQ_K; s += 64) {
    mapO[s] = 0.0f;
    ptsO[s * 3 + 0] = 0.0f;
    ptsO[s * 3 + 1] = 0.0f;
    ptsO[s * 3 + 2] = 0.0f;
  }
  if (lane == 0) numO[0] = (float)filled;
}

extern "C" void kernel_launch(void* const* d_in, const int* in_sizes, int n_in,
                              void* d_out, int out_size, void* d_ws,
                              size_t ws_size, hipStream_t stream) {
  const float* p1 = (const float*)d_in[0];
  const float* p2 = (const float*)d_in[1];
  float* out = (float*)d_out;

  if (ws_size < (size_t)WS_NEED) {
    bq_seq_kernel<<<BQ_N1 / 4, 256, 0, stream>>>(p1, p2, out);
    return;
  }

  char* ws = (char*)d_ws;
  unsigned int* meta = (unsigned int*)(ws + WS_META_OFF);
  float4* sorted = (float4*)(ws + WS_SORTED_OFF);

  bq_build_kernel<<<NPART, 1024, 0, stream>>>(p2, meta, sorted);
  bq_query_kernel<<<BQ_N1 / QPB, 256, 0, stream>>>(p1, p2, meta, sorted, out);
}

// Round 16
// 19.396 us; speedup vs baseline: 16.4792x; 1.0248x over previous
//
#include <hip/hip_runtime.h>
#include <cstdint>

// Ball query via 4-way-partitioned spatial grid, 2 dispatches.
// Round 16: sweep widened to 2 candidates/lane/iter (2 independent
// gather+FP chains in flight; 3 iters instead of 6) — r14/r15 jointly
// showed the query is partially latency-bound at 4 waves/SIMD.
// Decomposition (r12/r13 algebra): G~9.4 fixed, n~1.0/node, B~0.4, Q~8.1.
//
// Membership decision replicates the numpy-f32 reference EXACTLY (round 5):
//   norms:   pure rn  n = rn(rn(xx + yy) + zz)         (ufunc passes)
//   dot:     FMA chain d = fma(z1,z2, fma(y1,y2, rn(x1*x2)))  (sgemm K-loop)
//   combine: pure rn  d2 = rn(rn(n1+n2) - rn(2*dot))
// Compute kernels carry #pragma clang fp contract(off); dot uses __fmaf_rn.
// DO NOT ALTER THIS CHAIN.
//
// Hit-recording order in s_hits is IRRELEVANT (bitonic/rank epilogues sort
// by original index) -> the 2-wide sweep places B-hits after A-hits with
// popc arithmetic only.
//
// Outputs (flat float32, concatenated):
//   [0        : N1*K)      mapping (index as float; unfilled -> 0)
//   [N1*K     : N1*K+N1)   num_neighbors (min(count, K))
//   [N1*K+N1  : +N1*K*3)   gathered coords (unfilled -> 0)

#define BQ_K    32
#define BQ_N1   8192
#define BQ_N2   16384
#define GDIM    12
#define NCELLS  (GDIM * GDIM * GDIM)  // 1728
#define NPART   4
#define PPTS    (BQ_N2 / NPART)       // 4096 per partition
#define QPB     8                     // queries (32-lane groups) per block
#define HITCAP  128                   // hits cap (data max ~60)
#define GIDXCAP 384                   // candidate cap (avg ~182)

#define WS_META_OFF   0                      // uint[NCELLS*NPART] (27648)
#define WS_SORTED_OFF (NCELLS * NPART * 4)   // float4[BQ_N2] (16B-aligned)
#define WS_NEED       (WS_SORTED_OFF + BQ_N2 * 16)

__device__ __forceinline__ int bq_cell(float x, float y, float z) {
  int cx = min(max((int)(x * (float)GDIM), 0), GDIM - 1);
  int cy = min(max((int)(y * (float)GDIM), 0), GDIM - 1);
  int cz = min(max((int)(z * (float)GDIM), 0), GDIM - 1);
  return (cz * GDIM + cy) * GDIM + cx;
}

// Ascending 32-lane bitonic sort of one int per lane (within 32-lane group).
__device__ __forceinline__ int bq_bsort32(int v, int gl) {
#pragma unroll
  for (int k = 2; k <= 32; k <<= 1) {
#pragma unroll
    for (int j = k >> 1; j > 0; j >>= 1) {
      const int o = __shfl_xor(v, j, 32);
      const bool up = ((gl & k) == 0);
      const bool lower = ((gl & j) == 0);
      v = (up == lower) ? min(v, o) : max(v, o);
    }
  }
  return v;
}

// Grid build: unchanged (B ~ 0.4us).
__global__ __launch_bounds__(1024) void bq_build_kernel(
    const float* __restrict__ p2, unsigned int* __restrict__ meta,
    float4* __restrict__ sorted) {
  __shared__ int s_cnt[NCELLS];
  __shared__ int s_wave[16];
  const int t = threadIdx.x;
  const int lane = t & 63, wv = t >> 6;
  const int p = blockIdx.x;
  const int pbase = p * PPTS;

  for (int i = t; i < NCELLS; i += 1024) s_cnt[i] = 0;
  __syncthreads();

  float px[4], py[4], pz[4];
  int pc[4];
#pragma unroll
  for (int k = 0; k < 4; ++k) {
    const int i = pbase + k * 1024 + t;
    px[k] = p2[i * 3 + 0];
    py[k] = p2[i * 3 + 1];
    pz[k] = p2[i * 3 + 2];
    pc[k] = bq_cell(px[k], py[k], pz[k]);
    atomicAdd(&s_cnt[pc[k]], 1);
  }
  __syncthreads();

  const int cell0 = t * 2;
  int c0 = 0, c1 = 0;
  if (cell0 < NCELLS) {
    c0 = s_cnt[cell0];
    c1 = s_cnt[cell0 + 1];
  }
  const int sum = c0 + c1;
  int inc = sum;
#pragma unroll
  for (int d = 1; d < 64; d <<= 1) {
    int v = __shfl_up(inc, d);
    if (lane >= d) inc += v;
  }
  if (lane == 63) s_wave[wv] = inc;
  __syncthreads();
  if (t == 0) {
    int r = 0;
    for (int w = 0; w < 16; ++w) { int v = s_wave[w]; s_wave[w] = r; r += v; }
  }
  __syncthreads();
  const int excl = s_wave[wv] + (inc - sum);
  if (cell0 < NCELLS) {
    const int st0 = pbase + excl;
    const int st1 = pbase + excl + c0;
    meta[cell0 * NPART + p] = ((unsigned)c0 << 16) | (unsigned)st0;
    meta[(cell0 + 1) * NPART + p] = ((unsigned)c1 << 16) | (unsigned)st1;
    s_cnt[cell0] = st0;
    s_cnt[cell0 + 1] = st1;
  }
  __syncthreads();

#pragma unroll
  for (int k = 0; k < 4; ++k) {
    const int i = pbase + k * 1024 + t;
    const int slot = atomicAdd(&s_cnt[pc[k]], 1);
    sorted[slot] = make_float4(px[k], py[k], pz[k], __int_as_float(i));
  }
}

// Query: one 32-lane group per query; 2 groups per wave; 8 per block.
__global__ __launch_bounds__(256) void bq_query_kernel(
    const float* __restrict__ p1, const float* __restrict__ p2,
    const unsigned int* __restrict__ meta, const float4* __restrict__ sorted,
    float* __restrict__ out) {
#pragma clang fp contract(off)
  const int t = threadIdx.x;
  const int lane = t & 63;
  const int gl = t & 31;
  const int gid = t >> 5;
  const int half = lane >> 5;
  const int q = blockIdx.x * QPB + gid;

  __shared__ int s_gidx[QPB][GIDXCAP];
  __shared__ int s_hits[QPB][HITCAP];

  const float x1 = p1[q * 3 + 0];
  const float y1 = p1[q * 3 + 1];
  const float z1 = p1[q * 3 + 2];
  const float n1 = (x1 * x1 + y1 * y1) + z1 * z1;  // pure rn (contract off)
  const float rsq = (float)(0.08 * 0.08);
  const float prune_thr = 0.006413f;  // rsq*1.002 (safe AABB bound)

  const int cx = min(max((int)(x1 * (float)GDIM), 0), GDIM - 1);
  const int cy = min(max((int)(y1 * (float)GDIM), 0), GDIM - 1);
  const int cz = min(max((int)(z1 * (float)GDIM), 0), GDIM - 1);

  // Lane gl < 27 owns neighbor cell gl: ONE uint4 load covers its 4 runs.
  int c0 = 0, c1 = 0, c2 = 0, c3 = 0;
  int st0 = 0, st1 = 0, st2 = 0, st3 = 0;
  if (gl < 27) {
    const int nx = cx + (gl % 3) - 1;
    const int ny = cy + ((gl / 3) % 3) - 1;
    const int nz = cz + (gl / 9) - 1;
    if (nx >= 0 && nx < GDIM && ny >= 0 && ny < GDIM && nz >= 0 && nz < GDIM) {
      const float lx = (float)nx / 12.0f, hx = (float)(nx + 1) / 12.0f;
      const float ly = (float)ny / 12.0f, hy = (float)(ny + 1) / 12.0f;
      const float lz = (float)nz / 12.0f, hz = (float)(nz + 1) / 12.0f;
      const float dx = fmaxf(0.0f, fmaxf(lx - x1, x1 - hx));
      const float dy = fmaxf(0.0f, fmaxf(ly - y1, y1 - hy));
      const float dz = fmaxf(0.0f, fmaxf(lz - z1, z1 - hz));
      const float mind2 = dx * dx + dy * dy + dz * dz;
      if (mind2 <= prune_thr) {
        const int cc = (nz * GDIM + ny) * GDIM + nx;
        const uint4 m4 = *reinterpret_cast<const uint4*>(&meta[cc * NPART]);
        c0 = (int)(m4.x >> 16); st0 = (int)(m4.x & 0xFFFFu);
        c1 = (int)(m4.y >> 16); st1 = (int)(m4.y & 0xFFFFu);
        c2 = (int)(m4.z >> 16); st2 = (int)(m4.z & 0xFFFFu);
        c3 = (int)(m4.w >> 16); st3 = (int)(m4.w & 0xFFFFu);
      }
    }
  }
  // Width-32 inclusive scan of per-lane sums.
  const int lsum = c0 + c1 + c2 + c3;
  int inc = lsum;
#pragma unroll
  for (int d = 1; d < 32; d <<= 1) {
    int v = __shfl_up(inc, d, 32);
    if (gl >= d) inc += v;
  }
  const int T = __shfl(inc, 31, 32);
  const int pref0 = inc - lsum;
  const int pref1 = pref0 + c0;
  const int pref2 = pref1 + c1;
  const int pref3 = pref2 + c2;

  float* __restrict__ mapO = out + (size_t)q * BQ_K;
  float* __restrict__ numO = out + (size_t)BQ_N1 * BQ_K + q;
  float* __restrict__ ptsO =
      out + (size_t)BQ_N1 * BQ_K + BQ_N1 + (size_t)q * BQ_K * 3;

  const bool fast = (T <= GIDXCAP);
  int H = 0;
  if (fast) {
    // Materialize candidate table (each lane writes its 4 short runs).
    for (int k = 0; k < c0; ++k) s_gidx[gid][pref0 + k] = st0 + k;
    for (int k = 0; k < c1; ++k) s_gidx[gid][pref1 + k] = st1 + k;
    for (int k = 0; k < c2; ++k) s_gidx[gid][pref2 + k] = st2 + k;
    for (int k = 0; k < c3; ++k) s_gidx[gid][pref3 + k] = st3 + k;

    // Sweep: 64 candidates/iter (2 per lane, independent chains -> MLP).
    for (int s0 = 0; s0 < T; s0 += 64) {
      const int sA = s0 + gl;
      const int sB = s0 + 32 + gl;
      bool wA = false, wB = false;
      int idxA = 0, idxB = 0;
      if (sA < T) {
        const int g = s_gidx[gid][sA];
        const float4 pt = sorted[g];
        idxA = __float_as_int(pt.w);
        // EXACT reference FP chain (round 5) — do not alter.
        const float n2 = (pt.x * pt.x + pt.y * pt.y) + pt.z * pt.z;
        float dot = pt.x * x1;
        dot = __fmaf_rn(y1, pt.y, dot);
        dot = __fmaf_rn(z1, pt.z, dot);
        const float nsum = n1 + n2;
        const float twodot = 2.0f * dot;
        const float d2 = nsum - twodot;
        wA = (d2 <= rsq);
      }
      if (sB < T) {
        const int g = s_gidx[gid][sB];
        const float4 pt = sorted[g];
        idxB = __float_as_int(pt.w);
        // EXACT reference FP chain (round 5) — do not alter.
        const float n2 = (pt.x * pt.x + pt.y * pt.y) + pt.z * pt.z;
        float dot = pt.x * x1;
        dot = __fmaf_rn(y1, pt.y, dot);
        dot = __fmaf_rn(z1, pt.z, dot);
        const float nsum = n1 + n2;
        const float twodot = 2.0f * dot;
        const float d2 = nsum - twodot;
        wB = (d2 <= rsq);
      }
      const unsigned long long balA = __ballot(wA);
      const unsigned long long balB = __ballot(wB);
      const unsigned int bA = (unsigned int)(balA >> (half << 5));
      const unsigned int bB = (unsigned int)(balB >> (half << 5));
      if (bA | bB) {
        const int cA = (int)__popc(bA);
        // Order within s_hits is irrelevant (epilogues sort by index).
        if (wA) {
          const int pos = H + (int)__popc(bA & ((1u << gl) - 1u));
          if (pos < HITCAP) s_hits[gid][pos] = idxA;
        }
        if (wB) {
          const int pos = H + cA + (int)__popc(bB & ((1u << gl) - 1u));
          if (pos < HITCAP) s_hits[gid][pos] = idxB;
        }
        H += cA + (int)__popc(bB);
      }
    }
  }

  if (fast && H <= 64) {
    // Bitonic epilogue: sort two 32-vectors, merge, keep 32 smallest sorted.
    const int nh = min(H, BQ_K);
    int v0 = (gl < H) ? s_hits[gid][gl] : 0x7fffffff;
    int v1 = (gl + 32 < H) ? s_hits[gid][gl + 32] : 0x7fffffff;
    v0 = bq_bsort32(v0, gl);
    v1 = bq_bsort32(v1, gl);
    const int v1r = __shfl(v1, 31 - gl, 32);  // descending copy
    int m = min(v0, v1r);                     // 32 smallest, bitonic order
#pragma unroll
    for (int j = 16; j > 0; j >>= 1) {        // clean to ascending
      const int o = __shfl_xor(m, j, 32);
      m = ((gl & j) == 0) ? min(m, o) : max(m, o);
    }
    if (gl < nh) {
      mapO[gl] = (float)m;
      ptsO[gl * 3 + 0] = p2[m * 3 + 0];
      ptsO[gl * 3 + 1] = p2[m * 3 + 1];
      ptsO[gl * 3 + 2] = p2[m * 3 + 2];
    } else {
      mapO[gl] = 0.0f;
      ptsO[gl * 3 + 0] = 0.0f;
      ptsO[gl * 3 + 1] = 0.0f;
      ptsO[gl * 3 + 2] = 0.0f;
    }
    if (gl == 0) numO[0] = (float)nh;
  } else if (fast && H <= HITCAP) {
    // Rare 64 < H <= 128: rank-loop path (4 comparators). P ~ 0.
    const int nh = min(H, BQ_K);
    const int i0 = (gl < H) ? s_hits[gid][gl] : 0x7fffffff;
    const int i1 = (gl + 32 < H) ? s_hits[gid][gl + 32] : 0x7fffffff;
    const int i2 = (gl + 64 < H) ? s_hits[gid][gl + 64] : 0x7fffffff;
    const int i3 = (gl + 96 < H) ? s_hits[gid][gl + 96] : 0x7fffffff;
    int r0 = 0, r1 = 0, r2 = 0, r3 = 0;
    for (int j = 0; j < H; ++j) {
      const int bj = s_hits[gid][j];
      r0 += (bj < i0) ? 1 : 0;
      r1 += (bj < i1) ? 1 : 0;
      r2 += (bj < i2) ? 1 : 0;
      r3 += (bj < i3) ? 1 : 0;
    }
    if (gl < H && r0 < BQ_K) {
      mapO[r0] = (float)i0;
      ptsO[r0 * 3 + 0] = p2[i0 * 3 + 0];
      ptsO[r0 * 3 + 1] = p2[i0 * 3 + 1];
      ptsO[r0 * 3 + 2] = p2[i0 * 3 + 2];
    }
    if (gl + 32 < H && r1 < BQ_K) {
      mapO[r1] = (float)i1;
      ptsO[r1 * 3 + 0] = p2[i1 * 3 + 0];
      ptsO[r1 * 3 + 1] = p2[i1 * 3 + 1];
      ptsO[r1 * 3 + 2] = p2[i1 * 3 + 2];
    }
    if (gl + 64 < H && r2 < BQ_K) {
      mapO[r2] = (float)i2;
      ptsO[r2 * 3 + 0] = p2[i2 * 3 + 0];
      ptsO[r2 * 3 + 1] = p2[i2 * 3 + 1];
      ptsO[r2 * 3 + 2] = p2[i2 * 3 + 2];
    }
    if (gl + 96 < H && r3 < BQ_K) {
      mapO[r3] = (float)i3;
      ptsO[r3 * 3 + 0] = p2[i3 * 3 + 0];
      ptsO[r3 * 3 + 1] = p2[i3 * 3 + 1];
      ptsO[r3 * 3 + 2] = p2[i3 * 3 + 2];
    }
    if (gl >= nh) {
      mapO[gl] = 0.0f;
      ptsO[gl * 3 + 0] = 0.0f;
      ptsO[gl * 3 + 1] = 0.0f;
      ptsO[gl * 3 + 2] = 0.0f;
    }
    if (gl == 0) numO[0] = (float)nh;
  } else {
    // Exact 32-lane sequential fallback (capacity overflow; P ~ 0).
    int filled = 0;
    for (int base = 0; base < BQ_N2; base += 32) {
      const int j = base + gl;
      const float x2 = p2[j * 3 + 0];
      const float y2 = p2[j * 3 + 1];
      const float z2 = p2[j * 3 + 2];
      const float n2 = (x2 * x2 + y2 * y2) + z2 * z2;
      float dot = x2 * x1;
      dot = __fmaf_rn(y1, y2, dot);
      dot = __fmaf_rn(z1, z2, dot);
      const float d2 = (n1 + n2) - 2.0f * dot;
      const bool within = (d2 <= rsq);
      const unsigned int b32 =
          (unsigned int)(__ballot(within) >> (half << 5));
      if (b32) {
        const int rank = (int)__popc(b32 & ((1u << gl) - 1u));
        const int slot = filled + rank;
        if (within && slot < BQ_K) {
          mapO[slot] = (float)j;
          ptsO[slot * 3 + 0] = x2;
          ptsO[slot * 3 + 1] = y2;
          ptsO[slot * 3 + 2] = z2;
        }
        filled += (int)__popc(b32);
        if (filled >= BQ_K) { filled = BQ_K; break; }
      }
    }
    if (gl >= filled) {
      mapO[gl] = 0.0f;
      ptsO[gl * 3 + 0] = 0.0f;
      ptsO[gl * 3 + 1] = 0.0f;
      ptsO[gl * 3 + 2] = 0.0f;
    }
    if (gl == 0) numO[0] = (float)filled;
  }
}

// Round-5 brute-force kernel, whole-problem fallback if ws too small.
__global__ __launch_bounds__(256) void bq_seq_kernel(
    const float* __restrict__ p1, const float* __restrict__ p2,
    float* __restrict__ out) {
#pragma clang fp contract(off)
  const int lane = threadIdx.x & 63;
  const int wave = threadIdx.x >> 6;
  const int q = blockIdx.x * 4 + wave;
  const float x1 = p1[q * 3 + 0], y1 = p1[q * 3 + 1], z1 = p1[q * 3 + 2];
  const float n1 = (x1 * x1 + y1 * y1) + z1 * z1;
  const float rsq = (float)(0.08 * 0.08);
  float* mapO = out + (size_t)q * BQ_K;
  float* numO = out + (size_t)BQ_N1 * BQ_K + q;
  float* ptsO = out + (size_t)BQ_N1 * BQ_K + BQ_N1 + (size_t)q * BQ_K * 3;
  int filled = 0;
  for (int base = 0; base < BQ_N2; base += 64) {
    const int j = base + lane;
    const float x2 = p2[j * 3 + 0], y2 = p2[j * 3 + 1], z2 = p2[j * 3 + 2];
    const float n2 = (x2 * x2 + y2 * y2) + z2 * z2;
    float dot = x2 * x1;
    dot = __fmaf_rn(y1, y2, dot);
    dot = __fmaf_rn(z1, z2, dot);
    const float d2 = (n1 + n2) - 2.0f * dot;
    const bool within = (d2 <= rsq);
    const unsigned long long b = __ballot(within);
    if (b) {
      const int rank = (int)__popcll(b & ((1ull << lane) - 1ull));
      const int slot = filled + rank;
      if (within && slot < BQ_K) {
        mapO[slot] = (float)j;
        ptsO[slot * 3 + 0] = x2;
        ptsO[slot * 3 + 1] = y2;
        ptsO[slot * 3 + 2] = z2;
      }
      filled += (int)__popcll(b);
      if (filled >= BQ_K) { filled = BQ_K; break; }
    }
  }
  for (int s = filled + lane; s < BQ_K; s += 64) {
    mapO[s] = 0.0f;
    ptsO[s * 3 + 0] = 0.0f;
    ptsO[s * 3 + 1] = 0.0f;
    ptsO[s * 3 + 2] = 0.0f;
  }
  if (lane == 0) numO[0] = (float)filled;
}

extern "C" void kernel_launch(void* const* d_in, const int* in_sizes, int n_in,
                              void* d_out, int out_size, void* d_ws,
                              size_t ws_size, hipStream_t stream) {
  const float* p1 = (const float*)d_in[0];
  const float* p2 = (const float*)d_in[1];
  float* out = (float*)d_out;

  if (ws_size < (size_t)WS_NEED) {
    bq_seq_kernel<<<BQ_N1 / 4, 256, 0, stream>>>(p1, p2, out);
    return;
  }

  char* ws = (char*)d_ws;
  unsigned int* meta = (unsigned int*)(ws + WS_META_OFF);
  float4* sorted = (float4*)(ws + WS_SORTED_OFF);

  bq_build_kernel<<<NPART, 1024, 0, stream>>>(p2, meta, sorted);
  bq_query_kernel<<<BQ_N1 / QPB, 256, 0, stream>>>(p1, p2, meta, sorted, out);
}

// Round 17
// 19.373 us; speedup vs baseline: 16.4984x; 1.0012x over previous
//
#include <hip/hip_runtime.h>
#include <cstdint>

// Ball query via 4-way-partitioned spatial grid, 2 dispatches.
// Round 17: (a) 4-wide sweep (128 cand/iter, 4 independent gather+FP chains
// -> deeper MLP; avg T~182 means 2 iters); (b) hits stored as packed key
// (idx<<14 | g) so the epilogue re-fetches coords with ONE L2-hot float4
// load from sorted[] instead of 3 scattered p2 dword loads.
// Decomposition (r12/r13 algebra): G~9.4 fixed, n~1.0/node, B~0.4, Q~7.6
// (~3 issue + ~4.6 latency).
//
// Membership decision replicates the numpy-f32 reference EXACTLY (round 5):
//   norms:   pure rn  n = rn(rn(xx + yy) + zz)         (ufunc passes)
//   dot:     FMA chain d = fma(z1,z2, fma(y1,y2, rn(x1*x2)))  (sgemm K-loop)
//   combine: pure rn  d2 = rn(rn(n1+n2) - rn(2*dot))
// Compute kernels carry #pragma clang fp contract(off); dot uses __fmaf_rn.
// DO NOT ALTER THIS CHAIN.
//
// Hit order in s_hits is irrelevant (epilogues sort by key = idx-major).
//
// Outputs (flat float32, concatenated):
//   [0        : N1*K)      mapping (index as float; unfilled -> 0)
//   [N1*K     : N1*K+N1)   num_neighbors (min(count, K))
//   [N1*K+N1  : +N1*K*3)   gathered coords (unfilled -> 0)

#define BQ_K    32
#define BQ_N1   8192
#define BQ_N2   16384
#define GDIM    12
#define NCELLS  (GDIM * GDIM * GDIM)  // 1728
#define NPART   4
#define PPTS    (BQ_N2 / NPART)       // 4096 per partition
#define QPB     8                     // queries (32-lane groups) per block
#define HITCAP  128                   // hits cap (data max ~60)
#define GIDXCAP 384                   // candidate cap (avg ~182)
#define KEYPAD  0x7fffffff

#define WS_META_OFF   0                      // uint[NCELLS*NPART] (27648)
#define WS_SORTED_OFF (NCELLS * NPART * 4)   // float4[BQ_N2] (16B-aligned)
#define WS_NEED       (WS_SORTED_OFF + BQ_N2 * 16)

__device__ __forceinline__ int bq_cell(float x, float y, float z) {
  int cx = min(max((int)(x * (float)GDIM), 0), GDIM - 1);
  int cy = min(max((int)(y * (float)GDIM), 0), GDIM - 1);
  int cz = min(max((int)(z * (float)GDIM), 0), GDIM - 1);
  return (cz * GDIM + cy) * GDIM + cx;
}

// Ascending 32-lane bitonic sort of one int per lane (within 32-lane group).
__device__ __forceinline__ int bq_bsort32(int v, int gl) {
#pragma unroll
  for (int k = 2; k <= 32; k <<= 1) {
#pragma unroll
    for (int j = k >> 1; j > 0; j >>= 1) {
      const int o = __shfl_xor(v, j, 32);
      const bool up = ((gl & k) == 0);
      const bool lower = ((gl & j) == 0);
      v = (up == lower) ? min(v, o) : max(v, o);
    }
  }
  return v;
}

// Grid build: unchanged (B ~ 0.4us).
__global__ __launch_bounds__(1024) void bq_build_kernel(
    const float* __restrict__ p2, unsigned int* __restrict__ meta,
    float4* __restrict__ sorted) {
  __shared__ int s_cnt[NCELLS];
  __shared__ int s_wave[16];
  const int t = threadIdx.x;
  const int lane = t & 63, wv = t >> 6;
  const int p = blockIdx.x;
  const int pbase = p * PPTS;

  for (int i = t; i < NCELLS; i += 1024) s_cnt[i] = 0;
  __syncthreads();

  float px[4], py[4], pz[4];
  int pc[4];
#pragma unroll
  for (int k = 0; k < 4; ++k) {
    const int i = pbase + k * 1024 + t;
    px[k] = p2[i * 3 + 0];
    py[k] = p2[i * 3 + 1];
    pz[k] = p2[i * 3 + 2];
    pc[k] = bq_cell(px[k], py[k], pz[k]);
    atomicAdd(&s_cnt[pc[k]], 1);
  }
  __syncthreads();

  const int cell0 = t * 2;
  int c0 = 0, c1 = 0;
  if (cell0 < NCELLS) {
    c0 = s_cnt[cell0];
    c1 = s_cnt[cell0 + 1];
  }
  const int sum = c0 + c1;
  int inc = sum;
#pragma unroll
  for (int d = 1; d < 64; d <<= 1) {
    int v = __shfl_up(inc, d);
    if (lane >= d) inc += v;
  }
  if (lane == 63) s_wave[wv] = inc;
  __syncthreads();
  if (t == 0) {
    int r = 0;
    for (int w = 0; w < 16; ++w) { int v = s_wave[w]; s_wave[w] = r; r += v; }
  }
  __syncthreads();
  const int excl = s_wave[wv] + (inc - sum);
  if (cell0 < NCELLS) {
    const int st0 = pbase + excl;
    const int st1 = pbase + excl + c0;
    meta[cell0 * NPART + p] = ((unsigned)c0 << 16) | (unsigned)st0;
    meta[(cell0 + 1) * NPART + p] = ((unsigned)c1 << 16) | (unsigned)st1;
    s_cnt[cell0] = st0;
    s_cnt[cell0 + 1] = st1;
  }
  __syncthreads();

#pragma unroll
  for (int k = 0; k < 4; ++k) {
    const int i = pbase + k * 1024 + t;
    const int slot = atomicAdd(&s_cnt[pc[k]], 1);
    sorted[slot] = make_float4(px[k], py[k], pz[k], __int_as_float(i));
  }
}

// Query: one 32-lane group per query; 2 groups per wave; 8 per block.
__global__ __launch_bounds__(256) void bq_query_kernel(
    const float* __restrict__ p1, const float* __restrict__ p2,
    const unsigned int* __restrict__ meta, const float4* __restrict__ sorted,
    float* __restrict__ out) {
#pragma clang fp contract(off)
  const int t = threadIdx.x;
  const int lane = t & 63;
  const int gl = t & 31;
  const int gid = t >> 5;
  const int half = lane >> 5;
  const int q = blockIdx.x * QPB + gid;

  __shared__ int s_gidx[QPB][GIDXCAP];
  __shared__ int s_hits[QPB][HITCAP];  // packed key: (idx<<14) | g

  const float x1 = p1[q * 3 + 0];
  const float y1 = p1[q * 3 + 1];
  const float z1 = p1[q * 3 + 2];
  const float n1 = (x1 * x1 + y1 * y1) + z1 * z1;  // pure rn (contract off)
  const float rsq = (float)(0.08 * 0.08);
  const float prune_thr = 0.006413f;  // rsq*1.002 (safe AABB bound)

  const int cx = min(max((int)(x1 * (float)GDIM), 0), GDIM - 1);
  const int cy = min(max((int)(y1 * (float)GDIM), 0), GDIM - 1);
  const int cz = min(max((int)(z1 * (float)GDIM), 0), GDIM - 1);

  // Lane gl < 27 owns neighbor cell gl: ONE uint4 load covers its 4 runs.
  int c0 = 0, c1 = 0, c2 = 0, c3 = 0;
  int st0 = 0, st1 = 0, st2 = 0, st3 = 0;
  if (gl < 27) {
    const int nx = cx + (gl % 3) - 1;
    const int ny = cy + ((gl / 3) % 3) - 1;
    const int nz = cz + (gl / 9) - 1;
    if (nx >= 0 && nx < GDIM && ny >= 0 && ny < GDIM && nz >= 0 && nz < GDIM) {
      const float lx = (float)nx / 12.0f, hx = (float)(nx + 1) / 12.0f;
      const float ly = (float)ny / 12.0f, hy = (float)(ny + 1) / 12.0f;
      const float lz = (float)nz / 12.0f, hz = (float)(nz + 1) / 12.0f;
      const float dx = fmaxf(0.0f, fmaxf(lx - x1, x1 - hx));
      const float dy = fmaxf(0.0f, fmaxf(ly - y1, y1 - hy));
      const float dz = fmaxf(0.0f, fmaxf(lz - z1, z1 - hz));
      const float mind2 = dx * dx + dy * dy + dz * dz;
      if (mind2 <= prune_thr) {
        const int cc = (nz * GDIM + ny) * GDIM + nx;
        const uint4 m4 = *reinterpret_cast<const uint4*>(&meta[cc * NPART]);
        c0 = (int)(m4.x >> 16); st0 = (int)(m4.x & 0xFFFFu);
        c1 = (int)(m4.y >> 16); st1 = (int)(m4.y & 0xFFFFu);
        c2 = (int)(m4.z >> 16); st2 = (int)(m4.z & 0xFFFFu);
        c3 = (int)(m4.w >> 16); st3 = (int)(m4.w & 0xFFFFu);
      }
    }
  }
  // Width-32 inclusive scan of per-lane sums.
  const int lsum = c0 + c1 + c2 + c3;
  int inc = lsum;
#pragma unroll
  for (int d = 1; d < 32; d <<= 1) {
    int v = __shfl_up(inc, d, 32);
    if (gl >= d) inc += v;
  }
  const int T = __shfl(inc, 31, 32);
  const int pref0 = inc - lsum;
  const int pref1 = pref0 + c0;
  const int pref2 = pref1 + c1;
  const int pref3 = pref2 + c2;

  float* __restrict__ mapO = out + (size_t)q * BQ_K;
  float* __restrict__ numO = out + (size_t)BQ_N1 * BQ_K + q;
  float* __restrict__ ptsO =
      out + (size_t)BQ_N1 * BQ_K + BQ_N1 + (size_t)q * BQ_K * 3;

  const bool fast = (T <= GIDXCAP);
  int H = 0;
  if (fast) {
    // Materialize candidate table (each lane writes its 4 short runs).
    for (int k = 0; k < c0; ++k) s_gidx[gid][pref0 + k] = st0 + k;
    for (int k = 0; k < c1; ++k) s_gidx[gid][pref1 + k] = st1 + k;
    for (int k = 0; k < c2; ++k) s_gidx[gid][pref2 + k] = st2 + k;
    for (int k = 0; k < c3; ++k) s_gidx[gid][pref3 + k] = st3 + k;

    // Sweep: 128 candidates/iter (4 per lane, independent chains -> MLP).
    for (int s0 = 0; s0 < T; s0 += 128) {
      bool w[4] = {false, false, false, false};
      int key[4] = {0, 0, 0, 0};
#pragma unroll
      for (int u = 0; u < 4; ++u) {
        const int s = s0 + u * 32 + gl;
        if (s < T) {
          const int g = s_gidx[gid][s];
          const float4 pt = sorted[g];
          const int idx = __float_as_int(pt.w);
          key[u] = (idx << 14) | g;
          // EXACT reference FP chain (round 5) — do not alter.
          const float n2 = (pt.x * pt.x + pt.y * pt.y) + pt.z * pt.z;
          float dot = pt.x * x1;
          dot = __fmaf_rn(y1, pt.y, dot);
          dot = __fmaf_rn(z1, pt.z, dot);
          const float nsum = n1 + n2;
          const float twodot = 2.0f * dot;
          const float d2 = nsum - twodot;
          w[u] = (d2 <= rsq);
        }
      }
      unsigned int b[4];
#pragma unroll
      for (int u = 0; u < 4; ++u)
        b[u] = (unsigned int)(__ballot(w[u]) >> (half << 5));
      if (b[0] | b[1] | b[2] | b[3]) {
        int base = H;
#pragma unroll
        for (int u = 0; u < 4; ++u) {
          if (w[u]) {
            const int pos = base + (int)__popc(b[u] & ((1u << gl) - 1u));
            if (pos < HITCAP) s_hits[gid][pos] = key[u];
          }
          base += (int)__popc(b[u]);
        }
        H = base;
      }
    }
  }

  if (fast && H <= 64) {
    // Bitonic epilogue: sort two 32-vectors, merge, keep 32 smallest sorted.
    const int nh = min(H, BQ_K);
    int v0 = (gl < H) ? s_hits[gid][gl] : KEYPAD;
    int v1 = (gl + 32 < H) ? s_hits[gid][gl + 32] : KEYPAD;
    v0 = bq_bsort32(v0, gl);
    v1 = bq_bsort32(v1, gl);
    const int v1r = __shfl(v1, 31 - gl, 32);  // descending copy
    int m = min(v0, v1r);                     // 32 smallest, bitonic order
#pragma unroll
    for (int j = 16; j > 0; j >>= 1) {        // clean to ascending
      const int o = __shfl_xor(m, j, 32);
      m = ((gl & j) == 0) ? min(m, o) : max(m, o);
    }
    if (gl < nh) {
      const int g = m & 0x3FFF;
      const float4 pt = sorted[g];  // L2-hot (just swept)
      mapO[gl] = (float)(m >> 14);
      ptsO[gl * 3 + 0] = pt.x;
      ptsO[gl * 3 + 1] = pt.y;
      ptsO[gl * 3 + 2] = pt.z;
    } else {
      mapO[gl] = 0.0f;
      ptsO[gl * 3 + 0] = 0.0f;
      ptsO[gl * 3 + 1] = 0.0f;
      ptsO[gl * 3 + 2] = 0.0f;
    }
    if (gl == 0) numO[0] = (float)nh;
  } else if (fast && H <= HITCAP) {
    // Rare 64 < H <= 128: rank-loop on keys (order == idx order). P ~ 0.
    const int nh = min(H, BQ_K);
    int kk[4];
    kk[0] = (gl < H) ? s_hits[gid][gl] : KEYPAD;
    kk[1] = (gl + 32 < H) ? s_hits[gid][gl + 32] : KEYPAD;
    kk[2] = (gl + 64 < H) ? s_hits[gid][gl + 64] : KEYPAD;
    kk[3] = (gl + 96 < H) ? s_hits[gid][gl + 96] : KEYPAD;
    int r[4] = {0, 0, 0, 0};
    for (int j = 0; j < H; ++j) {
      const int bj = s_hits[gid][j];
      r[0] += (bj < kk[0]) ? 1 : 0;
      r[1] += (bj < kk[1]) ? 1 : 0;
      r[2] += (bj < kk[2]) ? 1 : 0;
      r[3] += (bj < kk[3]) ? 1 : 0;
    }
#pragma unroll
    for (int u = 0; u < 4; ++u) {
      if (gl + u * 32 < H && r[u] < BQ_K) {
        const int g = kk[u] & 0x3FFF;
        const float4 pt = sorted[g];
        mapO[r[u]] = (float)(kk[u] >> 14);
        ptsO[r[u] * 3 + 0] = pt.x;
        ptsO[r[u] * 3 + 1] = pt.y;
        ptsO[r[u] * 3 + 2] = pt.z;
      }
    }
    if (gl >= nh) {
      mapO[gl] = 0.0f;
      ptsO[gl * 3 + 0] = 0.0f;
      ptsO[gl * 3 + 1] = 0.0f;
      ptsO[gl * 3 + 2] = 0.0f;
    }
    if (gl == 0) numO[0] = (float)nh;
  } else {
    // Exact 32-lane sequential fallback (capacity overflow; P ~ 0).
    int filled = 0;
    for (int base = 0; base < BQ_N2; base += 32) {
      const int j = base + gl;
      const float x2 = p2[j * 3 + 0];
      const float y2 = p2[j * 3 + 1];
      const float z2 = p2[j * 3 + 2];
      const float n2 = (x2 * x2 + y2 * y2) + z2 * z2;
      float dot = x2 * x1;
      dot = __fmaf_rn(y1, y2, dot);
      dot = __fmaf_rn(z1, z2, dot);
      const float d2 = (n1 + n2) - 2.0f * dot;
      const bool within = (d2 <= rsq);
      const unsigned int b32 =
          (unsigned int)(__ballot(within) >> (half << 5));
      if (b32) {
        const int rank = (int)__popc(b32 & ((1u << gl) - 1u));
        const int slot = filled + rank;
        if (within && slot < BQ_K) {
          mapO[slot] = (float)j;
          ptsO[slot * 3 + 0] = x2;
          ptsO[slot * 3 + 1] = y2;
          ptsO[slot * 3 + 2] = z2;
        }
        filled += (int)__popc(b32);
        if (filled >= BQ_K) { filled = BQ_K; break; }
      }
    }
    if (gl >= filled) {
      mapO[gl] = 0.0f;
      ptsO[gl * 3 + 0] = 0.0f;
      ptsO[gl * 3 + 1] = 0.0f;
      ptsO[gl * 3 + 2] = 0.0f;
    }
    if (gl == 0) numO[0] = (float)filled;
  }
}

// Round-5 brute-force kernel, whole-problem fallback if ws too small.
__global__ __launch_bounds__(256) void bq_seq_kernel(
    const float* __restrict__ p1, const float* __restrict__ p2,
    float* __restrict__ out) {
#pragma clang fp contract(off)
  const int lane = threadIdx.x & 63;
  const int wave = threadIdx.x >> 6;
  const int q = blockIdx.x * 4 + wave;
  const float x1 = p1[q * 3 + 0], y1 = p1[q * 3 + 1], z1 = p1[q * 3 + 2];
  const float n1 = (x1 * x1 + y1 * y1) + z1 * z1;
  const float rsq = (float)(0.08 * 0.08);
  float* mapO = out + (size_t)q * BQ_K;
  float* numO = out + (size_t)BQ_N1 * BQ_K + q;
  float* ptsO = out + (size_t)BQ_N1 * BQ_K + BQ_N1 + (size_t)q * BQ_K * 3;
  int filled = 0;
  for (int base = 0; base < BQ_N2; base += 64) {
    const int j = base + lane;
    const float x2 = p2[j * 3 + 0], y2 = p2[j * 3 + 1], z2 = p2[j * 3 + 2];
    const float n2 = (x2 * x2 + y2 * y2) + z2 * z2;
    float dot = x2 * x1;
    dot = __fmaf_rn(y1, y2, dot);
    dot = __fmaf_rn(z1, z2, dot);
    const float d2 = (n1 + n2) - 2.0f * dot;
    const bool within = (d2 <= rsq);
    const unsigned long long b = __ballot(within);
    if (b) {
      const int rank = (int)__popcll(b & ((1ull << lane) - 1ull));
      const int slot = filled + rank;
      if (within && slot < BQ_K) {
        mapO[slot] = (float)j;
        ptsO[slot * 3 + 0] = x2;
        ptsO[slot * 3 + 1] = y2;
        ptsO[slot * 3 + 2] = z2;
      }
      filled += (int)__popcll(b);
      if (filled >= BQ_K) { filled = BQ_K; break; }
    }
  }
  for (int s = filled + lane; s < BQ_K; s += 64) {
    mapO[s] = 0.0f;
    ptsO[s * 3 + 0] = 0.0f;
    ptsO[s * 3 + 1] = 0.0f;
    ptsO[s * 3 + 2] = 0.0f;
  }
  if (lane == 0) numO[0] = (float)filled;
}

extern "C" void kernel_launch(void* const* d_in, const int* in_sizes, int n_in,
                              void* d_out, int out_size, void* d_ws,
                              size_t ws_size, hipStream_t stream) {
  const float* p1 = (const float*)d_in[0];
  const float* p2 = (const float*)d_in[1];
  float* out = (float*)d_out;

  if (ws_size < (size_t)WS_NEED) {
    bq_seq_kernel<<<BQ_N1 / 4, 256, 0, stream>>>(p1, p2, out);
    return;
  }

  char* ws = (char*)d_ws;
  unsigned int* meta = (unsigned int*)(ws + WS_META_OFF);
  float4* sorted = (float4*)(ws + WS_SORTED_OFF);

  bq_build_kernel<<<NPART, 1024, 0, stream>>>(p2, meta, sorted);
  bq_query_kernel<<<BQ_N1 / QPB, 256, 0, stream>>>(p1, p2, meta, sorted, out);
}